// Round 8
// baseline (20020.737 us; speedup 1.0000x reference)
//
#include <hip/hip_runtime.h>

#define TOK 4096
#define SEQ 512
#define BATCH 8
#define DIM 512
#define NHEAD 8
#define DK 64
#define FFD 2048

__device__ __forceinline__ float wave_max(float v) {
    for (int off = 32; off; off >>= 1) v = fmaxf(v, __shfl_xor(v, off, 64));
    return v;
}
__device__ __forceinline__ float wave_sum(float v) {
    for (int off = 32; off; off >>= 1) v += __shfl_xor(v, off, 64);
    return v;
}

// sentinel: ws too small (absmax would become ~524288 - unmistakable)
__global__ void VAKT_52226802319686_kernel(float* out, int n) {
    int i = blockIdx.x * 256 + threadIdx.x;
    if (i < n) out[i] = 524288.f;
}

__global__ void embed_r8(const int* cd, const int* cad, const float* cemb,
                         const float* caemb, float* x0, float* y) {
    int tok = blockIdx.x;
    int idx = cd[tok];
    int resp = (cad[tok] - idx) / 1000;
    for (int d = threadIdx.x; d < DIM; d += 256) {
        float e = cemb[(size_t)idx * DIM + d];
        x0[(size_t)tok * DIM + d] = e;
        y[(size_t)tok * DIM + d] = e + caemb[resp * DIM + d];
    }
}

__global__ void concat_r8(const float* X, const float* X0, float* H) {
    int tok = blockIdx.x;
    for (int d = threadIdx.x; d < 2 * DIM; d += 256) {
        H[(size_t)tok * (2 * DIM) + d] =
            (d < DIM) ? X[(size_t)tok * DIM + d] : X0[(size_t)tok * DIM + (d - DIM)];
    }
}

__global__ void add_ln_r8(const float* X, const float* Dl, const float* sc,
                          const float* bi, float* O) {
    int lane = threadIdx.x & 63, w = threadIdx.x >> 6;
    size_t row = (size_t)blockIdx.x * 4 + w;
    const float* xr = X + row * DIM;
    const float* dr = Dl + row * DIM;
    float v[8]; float sum = 0.f, sq = 0.f;
    for (int i = 0; i < 8; i++) {
        int d = i * 64 + lane;
        float t = xr[d] + dr[d];
        v[i] = t; sum += t; sq += t * t;
    }
    sum = wave_sum(sum); sq = wave_sum(sq);
    float mean = sum * (1.0f / 512.0f);
    float var = sq * (1.0f / 512.0f) - mean * mean;
    float rstd = rsqrtf(var + 1e-5f);
    float* orow = O + row * DIM;
    for (int i = 0; i < 8; i++) {
        int d = i * 64 + lane;
        orow[d] = (v[i] - mean) * rstd * sc[d] + bi[d];
    }
}

// C[M=4096,N] = A[M,K] @ B[K,N] + bias; fp32 throughout; optional relu
__global__ void gemm_r8(const float* A, const float* B, const float* bias,
                        float* C, int N, int K, int relu) {
    __shared__ float As[64][17];
    __shared__ float Bs[16][65];
    const int t = threadIdx.x;
    const int tx = t & 15, ty = t >> 4;
    const int bm0 = blockIdx.y * 64, bn0 = blockIdx.x * 64;
    float acc[4][4];
    for (int i = 0; i < 4; i++)
        for (int j = 0; j < 4; j++) acc[i][j] = 0.f;
    for (int k0 = 0; k0 < K; k0 += 16) {
        __syncthreads();
        for (int q = 0; q < 4; q++) {
            int idx = q * 256 + t;
            int r = idx >> 4, kk = idx & 15;
            As[r][kk] = A[(size_t)(bm0 + r) * K + k0 + kk];
            int kb = idx >> 6, nn = idx & 63;
            int gn = bn0 + nn;
            Bs[kb][nn] = (gn < N) ? B[(size_t)(k0 + kb) * N + gn] : 0.f;
        }
        __syncthreads();
        for (int kk = 0; kk < 16; kk++) {
            float ar[4], br[4];
            for (int i = 0; i < 4; i++) ar[i] = As[ty * 4 + i][kk];
            for (int j = 0; j < 4; j++) br[j] = Bs[kk][tx * 4 + j];
            for (int i = 0; i < 4; i++)
                for (int j = 0; j < 4; j++) acc[i][j] += ar[i] * br[j];
        }
    }
    for (int i = 0; i < 4; i++) {
        int row = bm0 + ty * 4 + i;
        for (int j = 0; j < 4; j++) {
            int col = bn0 + tx * 4 + j;
            if (col < N) {
                float v = acc[i][j] + bias[col];
                if (relu && v < 0.f) v = 0.f;
                C[(size_t)row * N + col] = v;
            }
        }
    }
}

__global__ void attn_r8(const float* Q, const float* K, const float* V,
                        const float* gam, float* O, int mask0zp) {
    const int t = threadIdx.x;
    const int lane = t & 63, w = t >> 6;
    const int chunk = blockIdx.x, h = blockIdx.y, b = blockIdx.z;
    const size_t base = (size_t)b * SEQ * DIM + (size_t)h * DK;
    float g = gam[h];
    float gamma = -((g > 20.f) ? g : log1pf(__expf(g)));

    for (int rr = 0; rr < 16; ++rr) {
        int row = chunk * 64 + w * 16 + rr;
        size_t orow = base + (size_t)row * DIM;
        if (mask0zp && row == 0) { O[orow + lane] = 0.f; continue; }
        int kmax = mask0zp ? row - 1 : row;
        int cmax = kmax >> 6;

        float qf = Q[orow + lane];
        float s[8];
        for (int c = 0; c < 8; c++) s[c] = 0.f;

        for (int c = 0; c <= cmax; ++c) {
            const float* kr = K + base + (size_t)(c * 64 + lane) * DIM;
            float acc = 0.f;
            for (int d = 0; d < 64; ++d) {
                acc += __shfl(qf, d, 64) * kr[d];
            }
            s[c] = acc;
        }
        float m = -1e30f;
        for (int c = 0; c <= cmax; ++c) {
            int j = c * 64 + lane;
            s[c] = (j <= kmax) ? s[c] * 0.125f : -1e30f;
            m = fmaxf(m, s[c]);
        }
        m = wave_max(m);
        float p[8]; float sum = 0.f;
        for (int c = 0; c <= cmax; ++c) {
            int j = c * 64 + lane;
            p[c] = (j <= kmax) ? __expf(s[c] - m) : 0.f;
            sum += p[c];
        }
        sum = wave_sum(sum);
        float inv = 1.0f / sum;
        float run = 0.f;
        float s2[8];
        for (int c = 0; c <= cmax; ++c) {
            float sc = p[c] * inv;
            for (int off = 1; off < 64; off <<= 1) {
                float tv = __shfl_up(sc, off, 64);
                if (lane >= off) sc += tv;
            }
            float distcum = run + sc;
            run += __shfl(sc, 63, 64);
            int j = c * 64 + lane;
            float rem = 1.0f - distcum;
            if (rem < 0.f) rem = 0.f;
            float pos = (float)(row - j);
            float prod = rem * pos;
            if (prod < 0.f) prod = 0.f;
            float te = __expf(sqrtf(prod) * gamma);
            te = fminf(fmaxf(te, 1e-5f), 1e5f);
            s2[c] = (j <= kmax) ? s[c] * te : -1e30f;
        }
        float m2 = -1e30f;
        for (int c = 0; c <= cmax; ++c) m2 = fmaxf(m2, s2[c]);
        m2 = wave_max(m2);
        float a[8]; float sum2 = 0.f;
        for (int c = 0; c <= cmax; ++c) {
            int j = c * 64 + lane;
            a[c] = (j <= kmax) ? __expf(s2[c] - m2) : 0.f;
            sum2 += a[c];
        }
        sum2 = wave_sum(sum2);
        float inv2 = 1.0f / sum2;
        float o = 0.f;
        for (int c = 0; c <= cmax; ++c) {
            int jcount = kmax - c * 64 + 1;
            if (jcount > 64) jcount = 64;
            const float* vp = V + base + (size_t)(c * 64) * DIM + lane;
            float av = a[c] * inv2;
            for (int jj = 0; jj < jcount; ++jj) {
                float aj = __shfl(av, jj, 64);
                o += aj * vp[(size_t)jj * DIM];
            }
        }
        O[orow + lane] = o;
    }
}

static void run_gemm(const float* A, const float* B, const float* bias, float* C,
                     int N, int K, int relu, hipStream_t stream) {
    dim3 g((N + 63) / 64, TOK / 64);
    gemm_r8<<<g, dim3(256), 0, stream>>>(A, B, bias, C, N, K, relu);
}

extern "C" void kernel_launch(void* const* d_in, const int* in_sizes, int n_in,
                              void* d_out, int out_size, void* d_ws, size_t ws_size,
                              hipStream_t stream) {
    (void)in_sizes; (void)n_in;
    const int* c_data    = (const int*)d_in[0];
    const int* ca_data   = (const int*)d_in[1];
    const float* c_emb   = (const float*)d_in[2];
    const float* ca_emb  = (const float*)d_in[3];
    const float* Wk  = (const float*)d_in[4];
    const float* bk  = (const float*)d_in[5];
    const float* Wv  = (const float*)d_in[6];
    const float* bv  = (const float*)d_in[7];
    const float* Wo  = (const float*)d_in[8];
    const float* bo  = (const float*)d_in[9];
    const float* gammas = (const float*)d_in[10];
    const float* ln1s = (const float*)d_in[11];
    const float* ln1b = (const float*)d_in[12];
    const float* W1  = (const float*)d_in[13];
    const float* b1  = (const float*)d_in[14];
    const float* W2  = (const float*)d_in[15];
    const float* b2  = (const float*)d_in[16];
    const float* ln2s = (const float*)d_in[17];
    const float* ln2b = (const float*)d_in[18];
    const float* oW0 = (const float*)d_in[19];
    const float* ob0 = (const float*)d_in[20];
    const float* oW1 = (const float*)d_in[21];
    const float* ob1 = (const float*)d_in[22];
    const float* oW2 = (const float*)d_in[23];
    const float* ob2 = (const float*)d_in[24];

    float* out = (float*)d_out;   // fp32 output, per reference output dtype

    const size_t MB = 1024 * 1024;
    if (ws_size < 64 * MB) {
        VAKT_52226802319686_kernel<<<dim3((out_size + 255) / 256), dim3(256), 0, stream>>>(out, out_size);
        return;
    }
    char* wsp = (char*)d_ws;
    float* x0b = (float*)(wsp);
    float* yb  = (float*)(wsp + 8 * MB);
    float* xb  = (float*)(wsp + 16 * MB);
    float* qb  = (float*)(wsp + 24 * MB);
    float* kb  = (float*)(wsp + 32 * MB);
    float* vb  = (float*)(wsp + 40 * MB);
    float* ao  = (float*)(wsp + 48 * MB);
    float* t1  = (float*)(wsp + 56 * MB);
    float* ffb = (float*)(wsp + 24 * MB);   // over q,k,v,ao (dead then)
    float* hcat = (float*)(wsp + 24 * MB);
    float* h1   = (float*)(wsp + 56 * MB);
    float* h2   = (float*)(wsp + 40 * MB);

    embed_r8<<<dim3(TOK), dim3(256), 0, stream>>>(c_data, ca_data, c_emb, ca_emb, x0b, yb);

    for (int li = 0; li < 6; ++li) {
        const float *query, *key, *values; float* outb; int m0; int pos;
        if (li == 0 || li == 1) { query = yb; key = x0b; values = yb; outb = yb; m0 = 0; pos = 1; }
        else if (li == 2) { query = x0b; key = x0b; values = x0b; outb = xb; m0 = 0; pos = 0; }
        else if (li == 3) { query = xb; key = xb; values = yb; outb = xb; m0 = 1; pos = 1; }
        else if (li == 4) { query = xb; key = xb; values = xb; outb = xb; m0 = 0; pos = 0; }
        else { query = xb; key = xb; values = yb; outb = xb; m0 = 1; pos = 1; }

        run_gemm(query,  Wk + (size_t)li * DIM * DIM, bk + li * DIM, qb, DIM, DIM, 0, stream);
        run_gemm(key,    Wk + (size_t)li * DIM * DIM, bk + li * DIM, kb, DIM, DIM, 0, stream);
        run_gemm(values, Wv + (size_t)li * DIM * DIM, bv + li * DIM, vb, DIM, DIM, 0, stream);
        attn_r8<<<dim3(SEQ / 64, NHEAD, BATCH), dim3(256), 0, stream>>>(
            qb, kb, vb, gammas + li * NHEAD, ao, m0);
        run_gemm(ao, Wo + (size_t)li * DIM * DIM, bo + li * DIM, t1, DIM, DIM, 0, stream);
        add_ln_r8<<<dim3(TOK / 4), dim3(256), 0, stream>>>(query, t1, ln1s + li * DIM, ln1b + li * DIM, outb);
        if (pos) {
            run_gemm(outb, W1 + (size_t)li * DIM * FFD, b1 + li * FFD, ffb, FFD, DIM, 1, stream);
            run_gemm(ffb, W2 + (size_t)li * FFD * DIM, b2 + li * DIM, t1, DIM, FFD, 0, stream);
            add_ln_r8<<<dim3(TOK / 4), dim3(256), 0, stream>>>(outb, t1, ln2s + li * DIM, ln2b + li * DIM, outb);
        }
    }

    concat_r8<<<dim3(TOK), dim3(256), 0, stream>>>(xb, x0b, hcat);
    run_gemm(hcat, oW0, ob0, h1, 512, 1024, 1, stream);
    run_gemm(h1, oW1, ob1, h2, 1024, 512, 1, stream);
    run_gemm(h2, oW2, ob2, out, 1000, 1024, 0, stream);  // fp32 out
}

// Round 9
// 18111.038 us; speedup vs baseline: 1.1054x; 1.1054x over previous
//
#include <hip/hip_runtime.h>

#define TOK 4096
#define SEQ 512
#define BATCH 8
#define DIM 512
#define NHEAD 8
#define DK 64
#define FFD 2048

__device__ __forceinline__ float wave_max(float v) {
    for (int off = 32; off; off >>= 1) v = fmaxf(v, __shfl_xor(v, off, 64));
    return v;
}
__device__ __forceinline__ float wave_sum(float v) {
    for (int off = 32; off; off >>= 1) v += __shfl_xor(v, off, 64);
    return v;
}

// sentinel: ws too small
__global__ void VAKT_52226802319686_kernel(float* out, int n) {
    int i = blockIdx.x * 256 + threadIdx.x;
    if (i < n) out[i] = 524288.f;
}

__global__ void embed_r9(const int* cd, const int* cad, const float* cemb,
                         const float* caemb, float* x0, float* y) {
    int tok = blockIdx.x;
    int idx = cd[tok];
    int resp = (cad[tok] - idx) / 1000;
    for (int d = threadIdx.x; d < DIM; d += 256) {
        float e = cemb[(size_t)idx * DIM + d];
        x0[(size_t)tok * DIM + d] = e;
        y[(size_t)tok * DIM + d] = e + caemb[resp * DIM + d];
    }
}

__global__ void concat_r9(const float* X, const float* X0, float* H) {
    int tok = blockIdx.x;
    for (int d = threadIdx.x; d < 2 * DIM; d += 256) {
        H[(size_t)tok * (2 * DIM) + d] =
            (d < DIM) ? X[(size_t)tok * DIM + d] : X0[(size_t)tok * DIM + (d - DIM)];
    }
}

__global__ void add_ln_r9(const float* X, const float* Dl, const float* sc,
                          const float* bi, float* O) {
    int lane = threadIdx.x & 63, w = threadIdx.x >> 6;
    size_t row = (size_t)blockIdx.x * 4 + w;
    const float* xr = X + row * DIM;
    const float* dr = Dl + row * DIM;
    float v[8]; float sum = 0.f, sq = 0.f;
    for (int i = 0; i < 8; i++) {
        int d = i * 64 + lane;
        float t = xr[d] + dr[d];
        v[i] = t; sum += t; sq += t * t;
    }
    sum = wave_sum(sum); sq = wave_sum(sq);
    float mean = sum * (1.0f / 512.0f);
    float var = sq * (1.0f / 512.0f) - mean * mean;
    float rstd = rsqrtf(var + 1e-5f);
    float* orow = O + row * DIM;
    for (int i = 0; i < 8; i++) {
        int d = i * 64 + lane;
        orow[d] = (v[i] - mean) * rstd * sc[d] + bi[d];
    }
}

__global__ void gemm_r9(const float* A, const float* B, const float* bias,
                        float* C, int N, int K, int relu) {
    __shared__ float As[64][17];
    __shared__ float Bs[16][65];
    const int t = threadIdx.x;
    const int tx = t & 15, ty = t >> 4;
    const int bm0 = blockIdx.y * 64, bn0 = blockIdx.x * 64;
    float acc[4][4];
    for (int i = 0; i < 4; i++)
        for (int j = 0; j < 4; j++) acc[i][j] = 0.f;
    for (int k0 = 0; k0 < K; k0 += 16) {
        __syncthreads();
        for (int q = 0; q < 4; q++) {
            int idx = q * 256 + t;
            int r = idx >> 4, kk = idx & 15;
            As[r][kk] = A[(size_t)(bm0 + r) * K + k0 + kk];
            int kb = idx >> 6, nn = idx & 63;
            int gn = bn0 + nn;
            Bs[kb][nn] = (gn < N) ? B[(size_t)(k0 + kb) * N + gn] : 0.f;
        }
        __syncthreads();
        for (int kk = 0; kk < 16; kk++) {
            float ar[4], br[4];
            for (int i = 0; i < 4; i++) ar[i] = As[ty * 4 + i][kk];
            for (int j = 0; j < 4; j++) br[j] = Bs[kk][tx * 4 + j];
            for (int i = 0; i < 4; i++)
                for (int j = 0; j < 4; j++) acc[i][j] += ar[i] * br[j];
        }
    }
    for (int i = 0; i < 4; i++) {
        int row = bm0 + ty * 4 + i;
        for (int j = 0; j < 4; j++) {
            int col = bn0 + tx * 4 + j;
            if (col < N) {
                float v = acc[i][j] + bias[col];
                if (relu && v < 0.f) v = 0.f;
                C[(size_t)row * N + col] = v;
            }
        }
    }
}

// KT[b,h][d][s] <- K[b*512+s][h*64+d]   (per-head transpose via LDS tile)
__global__ void ktrans_r9(const float* K, float* KT) {
    __shared__ float T[64][65];
    const int t = threadIdx.x;
    const int stile = blockIdx.x, h = blockIdx.y, b = blockIdx.z;
    for (int i = 0; i < 16; i++) {
        int idx = i * 256 + t;
        int srow = idx >> 6, d = idx & 63;
        T[srow][d] = K[(size_t)(b * SEQ + stile * 64 + srow) * DIM + h * DK + d];
    }
    __syncthreads();
    for (int i = 0; i < 16; i++) {
        int idx = i * 256 + t;
        int d = idx >> 6, scol = idx & 63;
        KT[((size_t)(b * NHEAD + h) * DK + d) * SEQ + stile * 64 + scol] = T[scol][d];
    }
}

// fused attention; scores read K via KT (coalesced). 32 rows per block.
__global__ void attn_r9(const float* Q, const float* KT, const float* V,
                        const float* gam, float* O, int mask0zp) {
    const int t = threadIdx.x;
    const int lane = t & 63, w = t >> 6;
    const int chunk = blockIdx.x, h = blockIdx.y, b = blockIdx.z;
    const size_t base = (size_t)b * SEQ * DIM + (size_t)h * DK;
    const size_t ktb = (size_t)(b * NHEAD + h) * DK * SEQ;
    float g = gam[h];
    float gamma = -((g > 20.f) ? g : log1pf(__expf(g)));

    for (int rr = 0; rr < 8; ++rr) {
        int row = chunk * 32 + w * 8 + rr;
        size_t orow = base + (size_t)row * DIM;
        if (mask0zp && row == 0) { O[orow + lane] = 0.f; continue; }
        int kmax = mask0zp ? row - 1 : row;
        int cmax = kmax >> 6;

        float qf = Q[orow + lane];
        float s[8];
        for (int c = 0; c < 8; c++) s[c] = 0.f;

        // coalesced: at fixed d, lanes read consecutive s-positions of KT
        for (int d = 0; d < 64; ++d) {
            float qd = __shfl(qf, d, 64);
            const float* kr = KT + ktb + (size_t)d * SEQ + lane;
            for (int c = 0; c <= cmax; ++c) s[c] += qd * kr[c * 64];
        }
        float m = -1e30f;
        for (int c = 0; c <= cmax; ++c) {
            int j = c * 64 + lane;
            s[c] = (j <= kmax) ? s[c] * 0.125f : -1e30f;
            m = fmaxf(m, s[c]);
        }
        m = wave_max(m);
        float p[8]; float sum = 0.f;
        for (int c = 0; c <= cmax; ++c) {
            int j = c * 64 + lane;
            p[c] = (j <= kmax) ? __expf(s[c] - m) : 0.f;
            sum += p[c];
        }
        sum = wave_sum(sum);
        float inv = 1.0f / sum;
        float run = 0.f;
        float s2[8];
        for (int c = 0; c <= cmax; ++c) {
            float sc = p[c] * inv;
            for (int off = 1; off < 64; off <<= 1) {
                float tv = __shfl_up(sc, off, 64);
                if (lane >= off) sc += tv;
            }
            float distcum = run + sc;
            run += __shfl(sc, 63, 64);
            int j = c * 64 + lane;
            float rem = 1.0f - distcum;
            if (rem < 0.f) rem = 0.f;
            float pos = (float)(row - j);
            float prod = rem * pos;
            if (prod < 0.f) prod = 0.f;
            float te = __expf(sqrtf(prod) * gamma);
            te = fminf(fmaxf(te, 1e-5f), 1e5f);
            s2[c] = (j <= kmax) ? s[c] * te : -1e30f;
        }
        float m2 = -1e30f;
        for (int c = 0; c <= cmax; ++c) m2 = fmaxf(m2, s2[c]);
        m2 = wave_max(m2);
        float a[8]; float sum2 = 0.f;
        for (int c = 0; c <= cmax; ++c) {
            int j = c * 64 + lane;
            a[c] = (j <= kmax) ? __expf(s2[c] - m2) : 0.f;
            sum2 += a[c];
        }
        sum2 = wave_sum(sum2);
        float inv2 = 1.0f / sum2;
        float o = 0.f;
        for (int c = 0; c <= cmax; ++c) {
            int jcount = kmax - c * 64 + 1;
            if (jcount > 64) jcount = 64;
            const float* vp = V + base + (size_t)(c * 64) * DIM + lane;
            float av = a[c] * inv2;
            for (int jj = 0; jj < jcount; ++jj) {
                float aj = __shfl(av, jj, 64);
                o += aj * vp[(size_t)jj * DIM];
            }
        }
        O[orow + lane] = o;
    }
}

static void run_gemm(const float* A, const float* B, const float* bias, float* C,
                     int N, int K, int relu, hipStream_t stream) {
    dim3 g((N + 63) / 64, TOK / 64);
    gemm_r9<<<g, dim3(256), 0, stream>>>(A, B, bias, C, N, K, relu);
}

extern "C" void kernel_launch(void* const* d_in, const int* in_sizes, int n_in,
                              void* d_out, int out_size, void* d_ws, size_t ws_size,
                              hipStream_t stream) {
    (void)in_sizes; (void)n_in;
    const int* c_data    = (const int*)d_in[0];
    const int* ca_data   = (const int*)d_in[1];
    const float* c_emb   = (const float*)d_in[2];
    const float* ca_emb  = (const float*)d_in[3];
    const float* Wk  = (const float*)d_in[4];
    const float* bk  = (const float*)d_in[5];
    const float* Wv  = (const float*)d_in[6];
    const float* bv  = (const float*)d_in[7];
    const float* Wo  = (const float*)d_in[8];
    const float* bo  = (const float*)d_in[9];
    const float* gammas = (const float*)d_in[10];
    const float* ln1s = (const float*)d_in[11];
    const float* ln1b = (const float*)d_in[12];
    const float* W1  = (const float*)d_in[13];
    const float* b1  = (const float*)d_in[14];
    const float* W2  = (const float*)d_in[15];
    const float* b2  = (const float*)d_in[16];
    const float* ln2s = (const float*)d_in[17];
    const float* ln2b = (const float*)d_in[18];
    const float* oW0 = (const float*)d_in[19];
    const float* ob0 = (const float*)d_in[20];
    const float* oW1 = (const float*)d_in[21];
    const float* ob1 = (const float*)d_in[22];
    const float* oW2 = (const float*)d_in[23];
    const float* ob2 = (const float*)d_in[24];

    float* out = (float*)d_out;

    const size_t MB = 1024 * 1024;
    if (ws_size < 64 * MB) {
        VAKT_52226802319686_kernel<<<dim3((out_size + 255) / 256), dim3(256), 0, stream>>>(out, out_size);
        return;
    }
    char* wsp = (char*)d_ws;
    float* x0b = (float*)(wsp);
    float* yb  = (float*)(wsp + 8 * MB);
    float* xb  = (float*)(wsp + 16 * MB);
    float* qb  = (float*)(wsp + 24 * MB);
    float* kb  = (float*)(wsp + 32 * MB);
    float* vb  = (float*)(wsp + 40 * MB);
    float* ao  = (float*)(wsp + 48 * MB);
    float* t1  = (float*)(wsp + 56 * MB);
    float* ktb = (float*)(wsp + 56 * MB);   // KT: exactly 8 MiB; t1 dead during attention
    float* ffb = (float*)(wsp + 24 * MB);   // over q,k,v,ao (dead then)
    float* hcat = (float*)(wsp + 24 * MB);
    float* h1   = (float*)(wsp + 56 * MB);
    float* h2   = (float*)(wsp + 40 * MB);

    embed_r9<<<dim3(TOK), dim3(256), 0, stream>>>(c_data, ca_data, c_emb, ca_emb, x0b, yb);

    for (int li = 0; li < 6; ++li) {
        const float *query, *key, *values; float* outb; int m0; int pos;
        if (li == 0 || li == 1) { query = yb; key = x0b; values = yb; outb = yb; m0 = 0; pos = 1; }
        else if (li == 2) { query = x0b; key = x0b; values = x0b; outb = xb; m0 = 0; pos = 0; }
        else if (li == 3) { query = xb; key = xb; values = yb; outb = xb; m0 = 1; pos = 1; }
        else if (li == 4) { query = xb; key = xb; values = xb; outb = xb; m0 = 0; pos = 0; }
        else { query = xb; key = xb; values = yb; outb = xb; m0 = 1; pos = 1; }

        run_gemm(query,  Wk + (size_t)li * DIM * DIM, bk + li * DIM, qb, DIM, DIM, 0, stream);
        run_gemm(key,    Wk + (size_t)li * DIM * DIM, bk + li * DIM, kb, DIM, DIM, 0, stream);
        run_gemm(values, Wv + (size_t)li * DIM * DIM, bv + li * DIM, vb, DIM, DIM, 0, stream);
        ktrans_r9<<<dim3(SEQ / 64, NHEAD, BATCH), dim3(256), 0, stream>>>(kb, ktb);
        attn_r9<<<dim3(SEQ / 32, NHEAD, BATCH), dim3(256), 0, stream>>>(
            qb, ktb, vb, gammas + li * NHEAD, ao, m0);
        run_gemm(ao, Wo + (size_t)li * DIM * DIM, bo + li * DIM, t1, DIM, DIM, 0, stream);
        add_ln_r9<<<dim3(TOK / 4), dim3(256), 0, stream>>>(query, t1, ln1s + li * DIM, ln1b + li * DIM, outb);
        if (pos) {
            run_gemm(outb, W1 + (size_t)li * DIM * FFD, b1 + li * FFD, ffb, FFD, DIM, 1, stream);
            run_gemm(ffb, W2 + (size_t)li * FFD * DIM, b2 + li * DIM, t1, DIM, FFD, 0, stream);
            add_ln_r9<<<dim3(TOK / 4), dim3(256), 0, stream>>>(outb, t1, ln2s + li * DIM, ln2b + li * DIM, outb);
        }
    }

    concat_r9<<<dim3(TOK), dim3(256), 0, stream>>>(xb, x0b, hcat);
    run_gemm(hcat, oW0, ob0, h1, 512, 1024, 1, stream);
    run_gemm(h1, oW1, ob1, h2, 1024, 512, 1, stream);
    run_gemm(h2, oW2, ob2, out, 1000, 1024, 0, stream);
}

// Round 10
// 5564.458 us; speedup vs baseline: 3.5980x; 3.2548x over previous
//
#include <hip/hip_runtime.h>

#define TOK 4096
#define SEQ 512
#define BATCH 8
#define DIM 512
#define NHEAD 8
#define DK 64
#define FFD 2048
#define RPW 4
#define RPB 16

__device__ __forceinline__ float wave_max(float v) {
    #pragma unroll
    for (int off = 32; off; off >>= 1) v = fmaxf(v, __shfl_xor(v, off, 64));
    return v;
}
__device__ __forceinline__ float wave_sum(float v) {
    #pragma unroll
    for (int off = 32; off; off >>= 1) v += __shfl_xor(v, off, 64);
    return v;
}

// sentinel: ws too small
__global__ void VAKT_52226802319686_kernel(float* out, int n) {
    int i = blockIdx.x * 256 + threadIdx.x;
    if (i < n) out[i] = 524288.f;
}

__global__ void embed_r10(const int* cd, const int* cad, const float* cemb,
                          const float* caemb, float* x0, float* y) {
    int tok = blockIdx.x;
    int idx = cd[tok];
    int resp = (cad[tok] - idx) / 1000;
    for (int d = threadIdx.x; d < DIM; d += 256) {
        float e = cemb[(size_t)idx * DIM + d];
        x0[(size_t)tok * DIM + d] = e;
        y[(size_t)tok * DIM + d] = e + caemb[resp * DIM + d];
    }
}

__global__ void concat_r10(const float* X, const float* X0, float* H) {
    int tok = blockIdx.x;
    for (int d = threadIdx.x; d < 2 * DIM; d += 256) {
        H[(size_t)tok * (2 * DIM) + d] =
            (d < DIM) ? X[(size_t)tok * DIM + d] : X0[(size_t)tok * DIM + (d - DIM)];
    }
}

__global__ void add_ln_r10(const float* X, const float* Dl, const float* sc,
                           const float* bi, float* O) {
    int lane = threadIdx.x & 63, w = threadIdx.x >> 6;
    size_t row = (size_t)blockIdx.x * 4 + w;
    const float* xr = X + row * DIM;
    const float* dr = Dl + row * DIM;
    float v[8]; float sum = 0.f, sq = 0.f;
    for (int i = 0; i < 8; i++) {
        int d = i * 64 + lane;
        float t = xr[d] + dr[d];
        v[i] = t; sum += t; sq += t * t;
    }
    sum = wave_sum(sum); sq = wave_sum(sq);
    float mean = sum * (1.0f / 512.0f);
    float var = sq * (1.0f / 512.0f) - mean * mean;
    float rstd = rsqrtf(var + 1e-5f);
    float* orow = O + row * DIM;
    for (int i = 0; i < 8; i++) {
        int d = i * 64 + lane;
        orow[d] = (v[i] - mean) * rstd * sc[d] + bi[d];
    }
}

__global__ void gemm_r10(const float* A, const float* B, const float* bias,
                         float* C, int N, int K, int relu) {
    __shared__ float As[64][17];
    __shared__ float Bs[16][65];
    const int t = threadIdx.x;
    const int tx = t & 15, ty = t >> 4;
    const int bm0 = blockIdx.y * 64, bn0 = blockIdx.x * 64;
    float acc[4][4];
    for (int i = 0; i < 4; i++)
        for (int j = 0; j < 4; j++) acc[i][j] = 0.f;
    for (int k0 = 0; k0 < K; k0 += 16) {
        __syncthreads();
        for (int q = 0; q < 4; q++) {
            int idx = q * 256 + t;
            int r = idx >> 4, kk = idx & 15;
            As[r][kk] = A[(size_t)(bm0 + r) * K + k0 + kk];
            int kb = idx >> 6, nn = idx & 63;
            int gn = bn0 + nn;
            Bs[kb][nn] = (gn < N) ? B[(size_t)(k0 + kb) * N + gn] : 0.f;
        }
        __syncthreads();
        for (int kk = 0; kk < 16; kk++) {
            float ar[4], br[4];
            for (int i = 0; i < 4; i++) ar[i] = As[ty * 4 + i][kk];
            for (int j = 0; j < 4; j++) br[j] = Bs[kk][tx * 4 + j];
            for (int i = 0; i < 4; i++)
                for (int j = 0; j < 4; j++) acc[i][j] += ar[i] * br[j];
        }
    }
    for (int i = 0; i < 4; i++) {
        int row = bm0 + ty * 4 + i;
        for (int j = 0; j < 4; j++) {
            int col = bn0 + tx * 4 + j;
            if (col < N) {
                float v = acc[i][j] + bias[col];
                if (relu && v < 0.f) v = 0.f;
                C[(size_t)row * N + col] = v;
            }
        }
    }
}

// LDS-tiled attention with distance decay. Block=(chunk of 16 rows, h, b);
// 4 waves x 4 rows. All per-row arrays compile-time indexed (registers).
__global__ __launch_bounds__(256) void attn_r10(const float* Q, const float* Kf,
                                                const float* V, const float* gam,
                                                float* O, int mask0zp) {
    __shared__ float tile[64 * 66];          // K tiles (pass1) then V tiles (pass2)
    __shared__ float qbuf[4][RPW][64];
    __shared__ float awbuf[4][RPW][64];
    const int t = threadIdx.x;
    const int lane = t & 63, w = t >> 6;
    const int chunk = blockIdx.x, h = blockIdx.y, b = blockIdx.z;
    const size_t base = (size_t)b * SEQ * DIM + (size_t)h * DK;
    const int row0 = chunk * RPB + w * RPW;
    float g = gam[h];
    float gamma = -((g > 20.f) ? g : log1pf(__expf(g)));
    const int kmax_blk = chunk * RPB + RPB - 1 - (mask0zp ? 1 : 0);
    const int cmax_blk = kmax_blk >> 6;

    // stage q rows (wave-local buffer)
    #pragma unroll
    for (int r = 0; r < RPW; ++r)
        qbuf[w][r][lane] = Q[base + (size_t)(row0 + r) * DIM + lane];

    float s[RPW][8];
    #pragma unroll
    for (int r = 0; r < RPW; ++r)
        #pragma unroll
        for (int c = 0; c < 8; ++c) s[r][c] = 0.f;

    const int jr = t >> 2, d0 = (t & 3) * 16;

    // ---- pass 1: scores ----
    #pragma unroll
    for (int c = 0; c < 8; ++c) {
        if (c <= cmax_blk) {                       // block-uniform
            __syncthreads();
            {   // stage K tile c: rows c*64+jr, dims d0..d0+15
                const float* src = Kf + base + (size_t)(c * 64 + jr) * DIM + d0;
                float4 a0 = ((const float4*)src)[0];
                float4 a1 = ((const float4*)src)[1];
                float4 a2 = ((const float4*)src)[2];
                float4 a3 = ((const float4*)src)[3];
                float* dst = tile + jr * 66 + d0;
                dst[0]=a0.x; dst[1]=a0.y; dst[2]=a0.z; dst[3]=a0.w;
                dst[4]=a1.x; dst[5]=a1.y; dst[6]=a1.z; dst[7]=a1.w;
                dst[8]=a2.x; dst[9]=a2.y; dst[10]=a2.z; dst[11]=a2.w;
                dst[12]=a3.x; dst[13]=a3.y; dst[14]=a3.z; dst[15]=a3.w;
            }
            __syncthreads();
            #pragma unroll
            for (int r = 0; r < RPW; ++r) {
                int kmaxr = row0 + r - mask0zp;
                if (c <= (kmaxr >> 6)) {
                    float acc = 0.f;
                    const float2* kt2 = (const float2*)(tile + lane * 66);
                    const float2* q2 = (const float2*)(qbuf[w][r]);
                    for (int dd = 0; dd < 32; ++dd) {
                        float2 kv = kt2[dd];
                        float2 qv = q2[dd];
                        acc += qv.x * kv.x + qv.y * kv.y;
                    }
                    s[r][c] = acc;
                }
            }
        }
    }

    // ---- softmax1 -> decay -> softmax2 (all in registers) ----
    #pragma unroll
    for (int r = 0; r < RPW; ++r) {
        const int row = row0 + r;
        const int kmaxr = row - mask0zp;
        float sv[8], pc[8];
        float m = -1e30f;
        #pragma unroll
        for (int c = 0; c < 8; ++c) {
            int j = c * 64 + lane;
            sv[c] = (j <= kmaxr) ? s[r][c] * 0.125f : -1e30f;
            m = fmaxf(m, sv[c]);
        }
        m = wave_max(m);
        float sum = 0.f;
        #pragma unroll
        for (int c = 0; c < 8; ++c) {
            int j = c * 64 + lane;
            pc[c] = (j <= kmaxr) ? __expf(sv[c] - m) : 0.f;
            sum += pc[c];
        }
        sum = wave_sum(sum);
        float inv = 1.0f / sum;
        float run = 0.f;
        #pragma unroll
        for (int c = 0; c < 8; ++c) {
            float sc = pc[c] * inv;
            #pragma unroll
            for (int off = 1; off < 64; off <<= 1) {
                float tv = __shfl_up(sc, off, 64);
                if (lane >= off) sc += tv;
            }
            float distcum = run + sc;
            run += __shfl(sc, 63, 64);
            int j = c * 64 + lane;
            float rem = 1.0f - distcum;
            if (rem < 0.f) rem = 0.f;
            float prod = rem * (float)(row - j);
            if (prod < 0.f) prod = 0.f;
            float te = __expf(sqrtf(prod) * gamma);
            te = fminf(fmaxf(te, 1e-5f), 1e5f);
            sv[c] = (j <= kmaxr) ? sv[c] * te : -1e30f;
        }
        float m2 = -1e30f;
        #pragma unroll
        for (int c = 0; c < 8; ++c) m2 = fmaxf(m2, sv[c]);
        m2 = wave_max(m2);
        float sum2 = 0.f;
        #pragma unroll
        for (int c = 0; c < 8; ++c) {
            int j = c * 64 + lane;
            pc[c] = (j <= kmaxr) ? __expf(sv[c] - m2) : 0.f;
            sum2 += pc[c];
        }
        sum2 = wave_sum(sum2);
        float inv2 = 1.0f / sum2;
        #pragma unroll
        for (int c = 0; c < 8; ++c) s[r][c] = pc[c] * inv2;   // final attn weights
    }

    // ---- pass 2: PV ----
    float o[RPW];
    #pragma unroll
    for (int r = 0; r < RPW; ++r) o[r] = 0.f;
    #pragma unroll
    for (int c = 0; c < 8; ++c) {
        if (c <= cmax_blk) {                       // block-uniform
            __syncthreads();
            {   // stage V tile c
                const float* src = V + base + (size_t)(c * 64 + jr) * DIM + d0;
                float4 a0 = ((const float4*)src)[0];
                float4 a1 = ((const float4*)src)[1];
                float4 a2 = ((const float4*)src)[2];
                float4 a3 = ((const float4*)src)[3];
                float* dst = tile + jr * 66 + d0;
                dst[0]=a0.x; dst[1]=a0.y; dst[2]=a0.z; dst[3]=a0.w;
                dst[4]=a1.x; dst[5]=a1.y; dst[6]=a1.z; dst[7]=a1.w;
                dst[8]=a2.x; dst[9]=a2.y; dst[10]=a2.z; dst[11]=a2.w;
                dst[12]=a3.x; dst[13]=a3.y; dst[14]=a3.z; dst[15]=a3.w;
            }
            __syncthreads();
            #pragma unroll
            for (int r = 0; r < RPW; ++r) {
                int kmaxr = row0 + r - mask0zp;
                if (c <= (kmaxr >> 6)) {
                    awbuf[w][r][lane] = s[r][c];   // wave-local transpose
                    float acc = o[r];
                    for (int jj = 0; jj < 64; ++jj)
                        acc += awbuf[w][r][jj] * tile[jj * 66 + lane];
                    o[r] = acc;
                }
            }
        }
    }
    #pragma unroll
    for (int r = 0; r < RPW; ++r) {
        int row = row0 + r;
        O[base + (size_t)row * DIM + lane] = (mask0zp && row == 0) ? 0.f : o[r];
    }
}

static void run_gemm(const float* A, const float* B, const float* bias, float* C,
                     int N, int K, int relu, hipStream_t stream) {
    dim3 g((N + 63) / 64, TOK / 64);
    gemm_r10<<<g, dim3(256), 0, stream>>>(A, B, bias, C, N, K, relu);
}

extern "C" void kernel_launch(void* const* d_in, const int* in_sizes, int n_in,
                              void* d_out, int out_size, void* d_ws, size_t ws_size,
                              hipStream_t stream) {
    (void)in_sizes; (void)n_in;
    const int* c_data    = (const int*)d_in[0];
    const int* ca_data   = (const int*)d_in[1];
    const float* c_emb   = (const float*)d_in[2];
    const float* ca_emb  = (const float*)d_in[3];
    const float* Wk  = (const float*)d_in[4];
    const float* bk  = (const float*)d_in[5];
    const float* Wv  = (const float*)d_in[6];
    const float* bv  = (const float*)d_in[7];
    const float* Wo  = (const float*)d_in[8];
    const float* bo  = (const float*)d_in[9];
    const float* gammas = (const float*)d_in[10];
    const float* ln1s = (const float*)d_in[11];
    const float* ln1b = (const float*)d_in[12];
    const float* W1  = (const float*)d_in[13];
    const float* b1  = (const float*)d_in[14];
    const float* W2  = (const float*)d_in[15];
    const float* b2  = (const float*)d_in[16];
    const float* ln2s = (const float*)d_in[17];
    const float* ln2b = (const float*)d_in[18];
    const float* oW0 = (const float*)d_in[19];
    const float* ob0 = (const float*)d_in[20];
    const float* oW1 = (const float*)d_in[21];
    const float* ob1 = (const float*)d_in[22];
    const float* oW2 = (const float*)d_in[23];
    const float* ob2 = (const float*)d_in[24];

    float* out = (float*)d_out;

    const size_t MB = 1024 * 1024;
    if (ws_size < 64 * MB) {
        VAKT_52226802319686_kernel<<<dim3((out_size + 255) / 256), dim3(256), 0, stream>>>(out, out_size);
        return;
    }
    char* wsp = (char*)d_ws;
    float* x0b = (float*)(wsp);
    float* yb  = (float*)(wsp + 8 * MB);
    float* xb  = (float*)(wsp + 16 * MB);
    float* qb  = (float*)(wsp + 24 * MB);
    float* kb  = (float*)(wsp + 32 * MB);
    float* vb  = (float*)(wsp + 40 * MB);
    float* ao  = (float*)(wsp + 48 * MB);
    float* t1  = (float*)(wsp + 56 * MB);
    float* ffb = (float*)(wsp + 24 * MB);   // over q,k,v,ao (dead then)
    float* hcat = (float*)(wsp + 24 * MB);
    float* h1   = (float*)(wsp + 56 * MB);
    float* h2   = (float*)(wsp + 40 * MB);

    embed_r10<<<dim3(TOK), dim3(256), 0, stream>>>(c_data, ca_data, c_emb, ca_emb, x0b, yb);

    for (int li = 0; li < 6; ++li) {
        const float *query, *key, *values; float* outb; int m0; int pos;
        if (li == 0 || li == 1) { query = yb; key = x0b; values = yb; outb = yb; m0 = 0; pos = 1; }
        else if (li == 2) { query = x0b; key = x0b; values = x0b; outb = xb; m0 = 0; pos = 0; }
        else if (li == 3) { query = xb; key = xb; values = yb; outb = xb; m0 = 1; pos = 1; }
        else if (li == 4) { query = xb; key = xb; values = xb; outb = xb; m0 = 0; pos = 0; }
        else { query = xb; key = xb; values = yb; outb = xb; m0 = 1; pos = 1; }

        run_gemm(query,  Wk + (size_t)li * DIM * DIM, bk + li * DIM, qb, DIM, DIM, 0, stream);
        run_gemm(key,    Wk + (size_t)li * DIM * DIM, bk + li * DIM, kb, DIM, DIM, 0, stream);
        run_gemm(values, Wv + (size_t)li * DIM * DIM, bv + li * DIM, vb, DIM, DIM, 0, stream);
        attn_r10<<<dim3(SEQ / RPB, NHEAD, BATCH), dim3(256), 0, stream>>>(
            qb, kb, vb, gammas + li * NHEAD, ao, m0);
        run_gemm(ao, Wo + (size_t)li * DIM * DIM, bo + li * DIM, t1, DIM, DIM, 0, stream);
        add_ln_r10<<<dim3(TOK / 4), dim3(256), 0, stream>>>(query, t1, ln1s + li * DIM, ln1b + li * DIM, outb);
        if (pos) {
            run_gemm(outb, W1 + (size_t)li * DIM * FFD, b1 + li * FFD, ffb, FFD, DIM, 1, stream);
            run_gemm(ffb, W2 + (size_t)li * FFD * DIM, b2 + li * DIM, t1, DIM, FFD, 0, stream);
            add_ln_r10<<<dim3(TOK / 4), dim3(256), 0, stream>>>(outb, t1, ln2s + li * DIM, ln2b + li * DIM, outb);
        }
    }

    concat_r10<<<dim3(TOK), dim3(256), 0, stream>>>(xb, x0b, hcat);
    run_gemm(hcat, oW0, ob0, h1, 512, 1024, 1, stream);
    run_gemm(h1, oW1, ob1, h2, 1024, 512, 1, stream);
    run_gemm(h2, oW2, ob2, out, 1000, 1024, 0, stream);
}

// Round 11
// 3227.595 us; speedup vs baseline: 6.2030x; 1.7240x over previous
//
#include <hip/hip_runtime.h>

#define TOK 4096
#define SEQ 512
#define BATCH 8
#define DIM 512
#define NHEAD 8
#define DK 64
#define FFD 2048
#define RPW 4
#define RPB 16

typedef unsigned short u16;
typedef float floatx4 __attribute__((ext_vector_type(4)));
typedef short shortx8 __attribute__((ext_vector_type(8)));

__device__ __forceinline__ u16 bfh(float f) {
    union { float f; unsigned u; } x; x.f = f;
    return (u16)((x.u + 0x7fffu + ((x.u >> 16) & 1u)) >> 16);
}
__device__ __forceinline__ float bff(u16 h) {
    union { unsigned u; float f; } x; x.u = (unsigned)h << 16; return x.f;
}
__device__ __forceinline__ float wave_max(float v) {
    #pragma unroll
    for (int off = 32; off; off >>= 1) v = fmaxf(v, __shfl_xor(v, off, 64));
    return v;
}
__device__ __forceinline__ float wave_sum(float v) {
    #pragma unroll
    for (int off = 32; off; off >>= 1) v += __shfl_xor(v, off, 64);
    return v;
}

// sentinel: ws too small
__global__ void VAKT_52226802319686_kernel(float* out, int n) {
    int i = blockIdx.x * 256 + threadIdx.x;
    if (i < n) out[i] = 524288.f;
}

__global__ void embed_r11(const int* cd, const int* cad, const float* cemb,
                          const float* caemb, float* x0, float* y) {
    int tok = blockIdx.x;
    int idx = cd[tok];
    int resp = (cad[tok] - idx) / 1000;
    for (int d = threadIdx.x; d < DIM; d += 256) {
        float e = cemb[(size_t)idx * DIM + d];
        x0[(size_t)tok * DIM + d] = e;
        y[(size_t)tok * DIM + d] = e + caemb[resp * DIM + d];
    }
}

__global__ void concat_r11(const float* X, const float* X0, float* H) {
    int tok = blockIdx.x;
    for (int d = threadIdx.x; d < 2 * DIM; d += 256) {
        H[(size_t)tok * (2 * DIM) + d] =
            (d < DIM) ? X[(size_t)tok * DIM + d] : X0[(size_t)tok * DIM + (d - DIM)];
    }
}

__global__ void add_ln_r11(const float* X, const float* Dl, const float* sc,
                           const float* bi, float* O) {
    int lane = threadIdx.x & 63, w = threadIdx.x >> 6;
    size_t row = (size_t)blockIdx.x * 4 + w;
    const float* xr = X + row * DIM;
    const float* dr = Dl + row * DIM;
    float v[8]; float sum = 0.f, sq = 0.f;
    for (int i = 0; i < 8; i++) {
        int d = i * 64 + lane;
        float t = xr[d] + dr[d];
        v[i] = t; sum += t; sq += t * t;
    }
    sum = wave_sum(sum); sq = wave_sum(sq);
    float mean = sum * (1.0f / 512.0f);
    float var = sq * (1.0f / 512.0f) - mean * mean;
    float rstd = rsqrtf(var + 1e-5f);
    float* orow = O + row * DIM;
    for (int i = 0; i < 8; i++) {
        int d = i * 64 + lane;
        orow[d] = (v[i] - mean) * rstd * sc[d] + bi[d];
    }
}

// weights W[K][N] fp32 -> Bt hi/lo u16 [Npad][K] (transposed + bf16-split)
__global__ __launch_bounds__(256) void wsplit(const float* W, u16* Bh, u16* Bl,
                                              int N, int K) {
    __shared__ float T[64][65];
    int t = threadIdx.x;
    int k0 = blockIdx.x * 64, n0 = blockIdx.y * 64;
    for (int i = 0; i < 16; i++) {
        int idx = i * 256 + t;
        int kr = idx >> 6, nc = idx & 63;
        int gn = n0 + nc;
        T[kr][nc] = (gn < N) ? W[(size_t)(k0 + kr) * N + gn] : 0.f;
    }
    __syncthreads();
    for (int i = 0; i < 16; i++) {
        int idx = i * 256 + t;
        int nr = idx >> 6, kc = idx & 63;
        float v = T[kc][nr];
        u16 h = bfh(v);
        float rem = v - bff(h);
        size_t o = (size_t)(n0 + nr) * K + k0 + kc;
        Bh[o] = h; Bl[o] = bfh(rem);
    }
}

// C[4096,N] = A[4096,K] @ Bt^T + bias. A fp32 (split on the fly), Bt pre-split u16 [*, Krow].
// mode: 0 = bias, 1 = bias+relu, 2 = accumulate into C.
__global__ __launch_bounds__(256) void gemm_mf(const float* A, const u16* Bth, const u16* Btl,
                                               int Krow, int koff, const float* bias,
                                               float* C, int N, int K, int mode) {
    __shared__ u16 Ah[64][40], Al[64][40];
    const int t = threadIdx.x;
    const int lane = t & 63, w = t >> 6;
    const int l16 = lane & 15, quad = lane >> 4;
    const int bm0 = blockIdx.y * 64, bn0 = blockIdx.x * 64;
    const int wm = (w & 1) * 32, wn = (w >> 1) * 32;
    const int ar = t >> 2, ac = (t & 3) * 8;

    floatx4 acc[2][2];
    #pragma unroll
    for (int mi = 0; mi < 2; mi++)
        #pragma unroll
        for (int ni = 0; ni < 2; ni++) acc[mi][ni] = (floatx4){0.f, 0.f, 0.f, 0.f};

    for (int k0 = 0; k0 < K; k0 += 32) {
        __syncthreads();
        {
            const float* src = A + (size_t)(bm0 + ar) * K + k0 + ac;
            float4 v0 = ((const float4*)src)[0];
            float4 v1 = ((const float4*)src)[1];
            float vv[8] = {v0.x, v0.y, v0.z, v0.w, v1.x, v1.y, v1.z, v1.w};
            unsigned hp[4], lp[4];
            #pragma unroll
            for (int i = 0; i < 4; i++) {
                u16 h0 = bfh(vv[2*i]),   l0 = bfh(vv[2*i]   - bff(bfh(vv[2*i])));
                u16 h1 = bfh(vv[2*i+1]), l1 = bfh(vv[2*i+1] - bff(bfh(vv[2*i+1])));
                hp[i] = (unsigned)h0 | ((unsigned)h1 << 16);
                lp[i] = (unsigned)l0 | ((unsigned)l1 << 16);
            }
            *(uint4*)&Ah[ar][ac] = make_uint4(hp[0], hp[1], hp[2], hp[3]);
            *(uint4*)&Al[ar][ac] = make_uint4(lp[0], lp[1], lp[2], lp[3]);
        }
        __syncthreads();
        shortx8 ahf[2], alf[2], bhf[2], blf[2];
        #pragma unroll
        for (int mi = 0; mi < 2; mi++) {
            ahf[mi] = *(const shortx8*)&Ah[wm + mi * 16 + l16][quad * 8];
            alf[mi] = *(const shortx8*)&Al[wm + mi * 16 + l16][quad * 8];
        }
        #pragma unroll
        for (int ni = 0; ni < 2; ni++) {
            size_t o = (size_t)(bn0 + wn + ni * 16 + l16) * Krow + koff + k0 + quad * 8;
            bhf[ni] = *(const shortx8*)(Bth + o);
            blf[ni] = *(const shortx8*)(Btl + o);
        }
        #pragma unroll
        for (int mi = 0; mi < 2; mi++)
            #pragma unroll
            for (int ni = 0; ni < 2; ni++) {
                acc[mi][ni] = __builtin_amdgcn_mfma_f32_16x16x32_bf16(ahf[mi], bhf[ni], acc[mi][ni], 0, 0, 0);
                acc[mi][ni] = __builtin_amdgcn_mfma_f32_16x16x32_bf16(ahf[mi], blf[ni], acc[mi][ni], 0, 0, 0);
                acc[mi][ni] = __builtin_amdgcn_mfma_f32_16x16x32_bf16(alf[mi], bhf[ni], acc[mi][ni], 0, 0, 0);
            }
    }
    #pragma unroll
    for (int ni = 0; ni < 2; ni++) {
        int col = bn0 + wn + ni * 16 + l16;
        if (col < N) {
            float bv = (mode == 2) ? 0.f : bias[col];
            #pragma unroll
            for (int mi = 0; mi < 2; mi++) {
                #pragma unroll
                for (int r = 0; r < 4; r++) {
                    int row = bm0 + wm + mi * 16 + quad * 4 + r;
                    size_t o = (size_t)row * N + col;
                    float v = acc[mi][ni][r] + bv;
                    if (mode == 1 && v < 0.f) v = 0.f;
                    if (mode == 2) v += C[o];
                    C[o] = v;
                }
            }
        }
    }
}

// LDS-tiled attention (unchanged from r10)
__global__ __launch_bounds__(256) void attn_r11(const float* Q, const float* Kf,
                                                const float* V, const float* gam,
                                                float* O, int mask0zp) {
    __shared__ float tile[64 * 66];
    __shared__ float qbuf[4][RPW][64];
    __shared__ float awbuf[4][RPW][64];
    const int t = threadIdx.x;
    const int lane = t & 63, w = t >> 6;
    const int chunk = blockIdx.x, h = blockIdx.y, b = blockIdx.z;
    const size_t base = (size_t)b * SEQ * DIM + (size_t)h * DK;
    const int row0 = chunk * RPB + w * RPW;
    float g = gam[h];
    float gamma = -((g > 20.f) ? g : log1pf(__expf(g)));
    const int kmax_blk = chunk * RPB + RPB - 1 - (mask0zp ? 1 : 0);
    const int cmax_blk = kmax_blk >> 6;

    #pragma unroll
    for (int r = 0; r < RPW; ++r)
        qbuf[w][r][lane] = Q[base + (size_t)(row0 + r) * DIM + lane];

    float s[RPW][8];
    #pragma unroll
    for (int r = 0; r < RPW; ++r)
        #pragma unroll
        for (int c = 0; c < 8; ++c) s[r][c] = 0.f;

    const int jr = t >> 2, d0 = (t & 3) * 16;

    #pragma unroll
    for (int c = 0; c < 8; ++c) {
        if (c <= cmax_blk) {
            __syncthreads();
            {
                const float* src = Kf + base + (size_t)(c * 64 + jr) * DIM + d0;
                float4 a0 = ((const float4*)src)[0];
                float4 a1 = ((const float4*)src)[1];
                float4 a2 = ((const float4*)src)[2];
                float4 a3 = ((const float4*)src)[3];
                float* dst = tile + jr * 66 + d0;
                dst[0]=a0.x; dst[1]=a0.y; dst[2]=a0.z; dst[3]=a0.w;
                dst[4]=a1.x; dst[5]=a1.y; dst[6]=a1.z; dst[7]=a1.w;
                dst[8]=a2.x; dst[9]=a2.y; dst[10]=a2.z; dst[11]=a2.w;
                dst[12]=a3.x; dst[13]=a3.y; dst[14]=a3.z; dst[15]=a3.w;
            }
            __syncthreads();
            #pragma unroll
            for (int r = 0; r < RPW; ++r) {
                int kmaxr = row0 + r - mask0zp;
                if (c <= (kmaxr >> 6)) {
                    float acc = 0.f;
                    const float2* kt2 = (const float2*)(tile + lane * 66);
                    const float2* q2 = (const float2*)(qbuf[w][r]);
                    for (int dd = 0; dd < 32; ++dd) {
                        float2 kv = kt2[dd];
                        float2 qv = q2[dd];
                        acc += qv.x * kv.x + qv.y * kv.y;
                    }
                    s[r][c] = acc;
                }
            }
        }
    }

    #pragma unroll
    for (int r = 0; r < RPW; ++r) {
        const int row = row0 + r;
        const int kmaxr = row - mask0zp;
        float sv[8], pc[8];
        float m = -1e30f;
        #pragma unroll
        for (int c = 0; c < 8; ++c) {
            int j = c * 64 + lane;
            sv[c] = (j <= kmaxr) ? s[r][c] * 0.125f : -1e30f;
            m = fmaxf(m, sv[c]);
        }
        m = wave_max(m);
        float sum = 0.f;
        #pragma unroll
        for (int c = 0; c < 8; ++c) {
            int j = c * 64 + lane;
            pc[c] = (j <= kmaxr) ? __expf(sv[c] - m) : 0.f;
            sum += pc[c];
        }
        sum = wave_sum(sum);
        float inv = 1.0f / sum;
        float run = 0.f;
        #pragma unroll
        for (int c = 0; c < 8; ++c) {
            float sc = pc[c] * inv;
            #pragma unroll
            for (int off = 1; off < 64; off <<= 1) {
                float tv = __shfl_up(sc, off, 64);
                if (lane >= off) sc += tv;
            }
            float distcum = run + sc;
            run += __shfl(sc, 63, 64);
            int j = c * 64 + lane;
            float rem = 1.0f - distcum;
            if (rem < 0.f) rem = 0.f;
            float prod = rem * (float)(row - j);
            if (prod < 0.f) prod = 0.f;
            float te = __expf(sqrtf(prod) * gamma);
            te = fminf(fmaxf(te, 1e-5f), 1e5f);
            sv[c] = (j <= kmaxr) ? sv[c] * te : -1e30f;
        }
        float m2 = -1e30f;
        #pragma unroll
        for (int c = 0; c < 8; ++c) m2 = fmaxf(m2, sv[c]);
        m2 = wave_max(m2);
        float sum2 = 0.f;
        #pragma unroll
        for (int c = 0; c < 8; ++c) {
            int j = c * 64 + lane;
            pc[c] = (j <= kmaxr) ? __expf(sv[c] - m2) : 0.f;
            sum2 += pc[c];
        }
        sum2 = wave_sum(sum2);
        float inv2 = 1.0f / sum2;
        #pragma unroll
        for (int c = 0; c < 8; ++c) s[r][c] = pc[c] * inv2;
    }

    float o[RPW];
    #pragma unroll
    for (int r = 0; r < RPW; ++r) o[r] = 0.f;
    #pragma unroll
    for (int c = 0; c < 8; ++c) {
        if (c <= cmax_blk) {
            __syncthreads();
            {
                const float* src = V + base + (size_t)(c * 64 + jr) * DIM + d0;
                float4 a0 = ((const float4*)src)[0];
                float4 a1 = ((const float4*)src)[1];
                float4 a2 = ((const float4*)src)[2];
                float4 a3 = ((const float4*)src)[3];
                float* dst = tile + jr * 66 + d0;
                dst[0]=a0.x; dst[1]=a0.y; dst[2]=a0.z; dst[3]=a0.w;
                dst[4]=a1.x; dst[5]=a1.y; dst[6]=a1.z; dst[7]=a1.w;
                dst[8]=a2.x; dst[9]=a2.y; dst[10]=a2.z; dst[11]=a2.w;
                dst[12]=a3.x; dst[13]=a3.y; dst[14]=a3.z; dst[15]=a3.w;
            }
            __syncthreads();
            #pragma unroll
            for (int r = 0; r < RPW; ++r) {
                int kmaxr = row0 + r - mask0zp;
                if (c <= (kmaxr >> 6)) {
                    awbuf[w][r][lane] = s[r][c];
                    float acc = o[r];
                    for (int jj = 0; jj < 64; ++jj)
                        acc += awbuf[w][r][jj] * tile[jj * 66 + lane];
                    o[r] = acc;
                }
            }
        }
    }
    #pragma unroll
    for (int r = 0; r < RPW; ++r) {
        int row = row0 + r;
        O[base + (size_t)row * DIM + lane] = (mask0zp && row == 0) ? 0.f : o[r];
    }
}

static void run_wsplit(const float* W, u16* Bh, u16* Bl, int N, int K, int Npad,
                       hipStream_t stream) {
    wsplit<<<dim3(K / 64, Npad / 64), dim3(256), 0, stream>>>(W, Bh, Bl, N, K);
}
static void run_gemm(const float* A, const u16* Bth, const u16* Btl, int Krow, int koff,
                     const float* bias, float* C, int N, int K, int mode, hipStream_t stream) {
    dim3 g((N + 63) / 64, TOK / 64);
    gemm_mf<<<g, dim3(256), 0, stream>>>(A, Bth, Btl, Krow, koff, bias, C, N, K, mode);
}

extern "C" void kernel_launch(void* const* d_in, const int* in_sizes, int n_in,
                              void* d_out, int out_size, void* d_ws, size_t ws_size,
                              hipStream_t stream) {
    (void)in_sizes; (void)n_in;
    const int* c_data    = (const int*)d_in[0];
    const int* ca_data   = (const int*)d_in[1];
    const float* c_emb   = (const float*)d_in[2];
    const float* ca_emb  = (const float*)d_in[3];
    const float* Wk  = (const float*)d_in[4];
    const float* bk  = (const float*)d_in[5];
    const float* Wv  = (const float*)d_in[6];
    const float* bv  = (const float*)d_in[7];
    const float* Wo  = (const float*)d_in[8];
    const float* bo  = (const float*)d_in[9];
    const float* gammas = (const float*)d_in[10];
    const float* ln1s = (const float*)d_in[11];
    const float* ln1b = (const float*)d_in[12];
    const float* W1  = (const float*)d_in[13];
    const float* b1  = (const float*)d_in[14];
    const float* W2  = (const float*)d_in[15];
    const float* b2  = (const float*)d_in[16];
    const float* ln2s = (const float*)d_in[17];
    const float* ln2b = (const float*)d_in[18];
    const float* oW0 = (const float*)d_in[19];
    const float* ob0 = (const float*)d_in[20];
    const float* oW1 = (const float*)d_in[21];
    const float* ob1 = (const float*)d_in[22];
    const float* oW2 = (const float*)d_in[23];
    const float* ob2 = (const float*)d_in[24];

    float* out = (float*)d_out;
    const size_t MB = 1024 * 1024;
    if (ws_size < 64 * MB) {
        VAKT_52226802319686_kernel<<<dim3((out_size + 255) / 256), dim3(256), 0, stream>>>(out, out_size);
        return;
    }
    char* wsp = (char*)d_ws;
    float* x0b = (float*)(wsp);             // 0-8
    float* yb  = (float*)(wsp + 8 * MB);    // 8-16
    float* xb  = (float*)(wsp + 16 * MB);   // 16-24
    float* qb  = (float*)(wsp + 24 * MB);   // 24-32
    float* kb  = (float*)(wsp + 32 * MB);   // 32-40
    float* vb  = (float*)(wsp + 40 * MB);   // 40-48
    float* ao  = (float*)(wsp + 48 * MB);   // 48-56
    float* t1  = (float*)(wsp + 56 * MB);   // 56-64
    // Bt regions (u16 hi/lo), liveness-overlapped:
    u16* btWk_h = (u16*)(wsp + 48 * MB);  u16* btWk_l = (u16*)(wsp + 49 * MB);  // dead before attn
    u16* btWv_h = (u16*)(wsp + 50 * MB);  u16* btWv_l = (u16*)(wsp + 51 * MB);
    u16* btWo_h = (u16*)(wsp + 24 * MB);  u16* btWo_l = (u16*)(wsp + 25 * MB);  // qb dead after attn
    u16* btW1_h = (u16*)(wsp + 24 * MB);  u16* btW1_l = (u16*)(wsp + 26 * MB);  // after Wo gemm
    u16* btW2_h = (u16*)(wsp + 28 * MB);  u16* btW2_l = (u16*)(wsp + 30 * MB);
    float* ffc  = (float*)(wsp + 32 * MB);  // 32-48: FFN chunk 4096x1024 (kb,vb dead)
    // head
    float* hcat = (float*)(wsp + 24 * MB);  // 24-40
    float* h1   = (float*)(wsp + 48 * MB);  // 48-56
    float* h2   = (float*)(wsp + 24 * MB);  // 24-40 (hcat dead after oW0)
    u16* btH_h  = (u16*)(wsp + 40 * MB);
    u16* btH_l  = (u16*)(wsp + 42 * MB);

    embed_r11<<<dim3(TOK), dim3(256), 0, stream>>>(c_data, ca_data, c_emb, ca_emb, x0b, yb);

    for (int li = 0; li < 6; ++li) {
        const float *query, *key, *values; float* outb; int m0; int pos;
        if (li == 0 || li == 1) { query = yb; key = x0b; values = yb; outb = yb; m0 = 0; pos = 1; }
        else if (li == 2) { query = x0b; key = x0b; values = x0b; outb = xb; m0 = 0; pos = 0; }
        else if (li == 3) { query = xb; key = xb; values = yb; outb = xb; m0 = 1; pos = 1; }
        else if (li == 4) { query = xb; key = xb; values = xb; outb = xb; m0 = 0; pos = 0; }
        else { query = xb; key = xb; values = yb; outb = xb; m0 = 1; pos = 1; }

        run_wsplit(Wk + (size_t)li * DIM * DIM, btWk_h, btWk_l, DIM, DIM, DIM, stream);
        run_wsplit(Wv + (size_t)li * DIM * DIM, btWv_h, btWv_l, DIM, DIM, DIM, stream);
        run_gemm(query, btWk_h, btWk_l, DIM, 0, bk + li * DIM, qb, DIM, DIM, 0, stream);
        const float* kb_use = qb;
        if (key != query) {
            run_gemm(key, btWk_h, btWk_l, DIM, 0, bk + li * DIM, kb, DIM, DIM, 0, stream);
            kb_use = kb;
        }
        run_gemm(values, btWv_h, btWv_l, DIM, 0, bv + li * DIM, vb, DIM, DIM, 0, stream);
        attn_r11<<<dim3(SEQ / RPB, NHEAD, BATCH), dim3(256), 0, stream>>>(
            qb, kb_use, vb, gammas + li * NHEAD, ao, m0);
        run_wsplit(Wo + (size_t)li * DIM * DIM, btWo_h, btWo_l, DIM, DIM, DIM, stream);
        run_gemm(ao, btWo_h, btWo_l, DIM, 0, bo + li * DIM, t1, DIM, DIM, 0, stream);
        add_ln_r11<<<dim3(TOK / 4), dim3(256), 0, stream>>>(query, t1, ln1s + li * DIM, ln1b + li * DIM, outb);
        if (pos) {
            run_wsplit(W1 + (size_t)li * DIM * FFD, btW1_h, btW1_l, FFD, DIM, FFD, stream);
            run_wsplit(W2 + (size_t)li * FFD * DIM, btW2_h, btW2_l, DIM, FFD, DIM, stream);
            for (int c = 0; c < 2; ++c) {
                run_gemm(outb, btW1_h + (size_t)c * 1024 * DIM, btW1_l + (size_t)c * 1024 * DIM,
                         DIM, 0, b1 + li * FFD + c * 1024, ffc, 1024, DIM, 1, stream);
                run_gemm(ffc, btW2_h, btW2_l, FFD, c * 1024, b2 + li * DIM, t1,
                         DIM, 1024, (c == 0) ? 0 : 2, stream);
            }
            add_ln_r11<<<dim3(TOK / 4), dim3(256), 0, stream>>>(outb, t1, ln2s + li * DIM, ln2b + li * DIM, outb);
        }
    }

    concat_r11<<<dim3(TOK), dim3(256), 0, stream>>>(xb, x0b, hcat);
    run_wsplit(oW0, btH_h, btH_l, 512, 1024, 512, stream);
    run_gemm(hcat, btH_h, btH_l, 1024, 0, ob0, h1, 512, 1024, 1, stream);
    run_wsplit(oW1, btH_h, btH_l, 1024, 512, 1024, stream);
    run_gemm(h1, btH_h, btH_l, 512, 0, ob1, h2, 1024, 512, 1, stream);
    run_wsplit(oW2, btH_h, btH_l, 1000, 1024, 1024, stream);
    run_gemm(h2, btH_h, btH_l, 1024, 0, ob2, out, 1000, 1024, 0, stream);
}